// Round 7
// baseline (62.159 us; speedup 1.0000x reference)
//
#include <hip/hip_runtime.h>

// NovelKQRAttention — algebraically collapsed, 3-dispatch chain.
// energy = a[...,q,None] + b[...,None,k]; softmax over k => a cancels,
// attn = softmax_k(b) independent of q => deform-conv path is dead,
// attention output constant over spatial dims.
//
// Further collapse: PV[o,h,c] = sum_{e in head h} proj_w[o,h*64+e]*value_w[h*64+e,c]
//   => po[n,o] = sum_{h,c} PV[o,h,c]*wx[n,h,c]   (removes the ov stage)
// PV depends only on weights, bpart only on x+key weights => one dispatch,
// disjoint block ranges, no ordering needed.
//
//   D1 k_head   : blocks [0,32)   bpart CHN=4 (144-ch chunks, kb-slice inline)
//                 blocks [32,1328) PV build (16o x 1h x 144c tiles)
//   D2 k_swx    : 4-chunk-sum (L2-resident) + softmax in LDS + wx reduction
//   D3 k_pofinal: po = PV[o]·wx[n] (5184-dot) + proj_b; out row = gamma*po + x row

#define CCH 576
#define NH 9
#define HW 4096   // 64*64
#define KHW 1024  // 32*32
#define W 64
#define CHN 4     // channel chunks
#define CPC 144   // channels per chunk
#define PVSZ (CCH * NH * CCH)   // 2,985,984 floats

// ws float offsets
#define WS_PV    0
#define WS_BPART PVSZ                    // 4*2*9*1024 = 73728
#define WS_WX    (PVSZ + 73728)          // 2*9*576    = 10368

// D1: 32 bpart blocks + 1296 pv blocks = 1328 blocks, 256 threads.
__global__ void k_head(const float* __restrict__ x, const float* __restrict__ key_w,
                       const float* __restrict__ appr_bias,
                       const float* __restrict__ value_w, const float* __restrict__ proj_w,
                       float* __restrict__ ws) {
    __shared__ float smem[64 * CPC + 16 * 64];   // 40 KB (pv role); bpart uses a prefix
    float* bpart = ws + WS_BPART;
    float* pv    = ws + WS_PV;
    const int bid = blockIdx.x;
    const int tid = threadIdx.x;

    if (bid < 32) {
        // ---- bpart role: bid = kblk(4) | n(1) | ch(2) ----
        int kblk = bid & 3, n = (bid >> 2) & 1, ch = bid >> 3;
        int c0 = ch * CPC, k0 = kblk * 256;
        float* ab  = smem;            // 576
        float* kbs = smem + 576;      // 9*144 = 1296
        for (int i = tid; i < CCH; i += 256) ab[i] = appr_bias[i];
        __syncthreads();
        for (int t = tid; t < NH * CPC; t += 256) {
            int h = t / CPC, cl = t % CPC;
            float s = 0.f;
            #pragma unroll 8
            for (int e = 0; e < 64; ++e)
                s += ab[h * 64 + e] * key_w[(size_t)(h * 64 + e) * CCH + c0 + cl];
            kbs[t] = s;
        }
        __syncthreads();

        int k = k0 + tid;
        int ky = k >> 5, kx = k & 31;
        const float* xb = x + (size_t)n * CCH * HW + (size_t)c0 * HW + (size_t)(ky * 2) * W + kx * 2;
        float acc[NH];
        #pragma unroll
        for (int h = 0; h < NH; ++h) acc[h] = 0.f;
        #pragma unroll 16
        for (int cl = 0; cl < CPC; ++cl) {
            float xv = xb[(size_t)cl * HW];
            #pragma unroll
            for (int h = 0; h < NH; ++h) acc[h] += kbs[h * CPC + cl] * xv;
        }
        // layout bpart[ch][n][h][k]
        #pragma unroll
        for (int h = 0; h < NH; ++h)
            bpart[(((size_t)ch * 2 + n) * NH + h) * KHW + k] = acc[h];
    } else {
        // ---- PV role: r = (bo 36) x (h 9) x (ct 4) ----
        int r = bid - 32;
        int bo = r % 36;          // o-tile of 16
        int h  = (r / 36) % NH;
        int ct = r / 324;         // c-tile of 144
        int o0 = bo * 16, c0 = ct * CPC;
        float* vw = smem;               // [64][144]
        float* pw = smem + 64 * CPC;    // [16][64]
        for (int i = tid; i < 64 * CPC; i += 256) {
            int e = i / CPC, cc = i % CPC;
            vw[i] = value_w[(size_t)(h * 64 + e) * CCH + c0 + cc];
        }
        for (int i = tid; i < 16 * 64; i += 256) {
            int oi = i >> 6, e = i & 63;
            pw[i] = proj_w[(size_t)(o0 + oi) * CCH + h * 64 + e];
        }
        __syncthreads();
        for (int i = tid; i < 16 * CPC; i += 256) {
            int oi = i / CPC, cc = i % CPC;
            float acc = 0.f;
            #pragma unroll 16
            for (int e = 0; e < 64; ++e)
                acc += pw[oi * 64 + e] * vw[e * CPC + cc];
            pv[(size_t)(o0 + oi) * (NH * CCH) + h * CCH + c0 + cc] = acc;
        }
    }
}

// D2: grid (144, 2 n), block 256 (4 waves).
// A: sum 4 bpart chunks into LDS sm[9][1024] (bpart is 2.3 MB -> L2-resident).
// B: per-wave softmax of disjoint head rows.
// C: wave wv owns channel c = bid.x*4+wv; wx[n,h,c] = sum_k p[h,k]*x_kv[n,c,k].
__global__ void k_swx(const float* __restrict__ x, const float* __restrict__ ws_bpart,
                      float* __restrict__ wx) {
    int n = blockIdx.y;
    int tid = threadIdx.x;
    int wv = tid >> 6, ln = tid & 63;
    __shared__ float sm[NH * KHW];   // 36 KB

    const float* bp = ws_bpart + (size_t)n * NH * KHW;
    for (int i = tid; i < NH * KHW; i += 256) {
        float v = 0.f;
        #pragma unroll
        for (int ch = 0; ch < CHN; ++ch)
            v += bp[(size_t)ch * 2 * NH * KHW + i];
        sm[i] = v;
    }
    __syncthreads();

    for (int h = wv; h < NH; h += 4) {
        float* row = sm + h * KHW;
        float m = -1e30f;
        #pragma unroll
        for (int j = 0; j < 16; ++j) m = fmaxf(m, row[ln + 64 * j]);
        #pragma unroll
        for (int off = 32; off >= 1; off >>= 1) m = fmaxf(m, __shfl_xor(m, off, 64));
        float s = 0.f;
        #pragma unroll
        for (int j = 0; j < 16; ++j) {
            float e = __expf(row[ln + 64 * j] - m);
            row[ln + 64 * j] = e;
            s += e;
        }
        #pragma unroll
        for (int off = 32; off >= 1; off >>= 1) s += __shfl_xor(s, off, 64);
        float inv = 1.f / s;
        #pragma unroll
        for (int j = 0; j < 16; ++j) row[ln + 64 * j] *= inv;
    }
    __syncthreads();

    int c = blockIdx.x * 4 + wv;
    const float* xb = x + ((size_t)n * CCH + c) * HW;
    float acc[NH];
    #pragma unroll
    for (int h = 0; h < NH; ++h) acc[h] = 0.f;
    #pragma unroll 4
    for (int j = 0; j < 16; ++j) {
        int k = ln + 64 * j;
        int ky = k >> 5, kx = k & 31;
        float xv = xb[(size_t)(ky * 2) * W + kx * 2];
        #pragma unroll
        for (int h = 0; h < NH; ++h) acc[h] += sm[h * KHW + k] * xv;
    }
    #pragma unroll
    for (int h = 0; h < NH; ++h) {
        float v = acc[h];
        #pragma unroll
        for (int off = 32; off >= 1; off >>= 1) v += __shfl_xor(v, off, 64);
        if (ln == 0) wx[((size_t)n * NH + h) * CCH + c] = v;   // layout [n][h][c]
    }
}

// D3: grid 1152 (block per (n,o) row), block 256.
// po = PV[o,:,:] . wx[n,:,:] (5184-dot) + proj_b[o]; stream out row = x + gamma*po.
__global__ void k_pofinal(const float* __restrict__ pv, const float* __restrict__ proj_b,
                          const float* __restrict__ wx, const float* __restrict__ x,
                          const float* __restrict__ gamma, float* __restrict__ out) {
    int b = blockIdx.x;
    int n = b / CCH, o = b % CCH;
    int t = threadIdx.x;
    int wv = t >> 6, ln = t & 63;
    __shared__ float pr[4];

    const float* pvr = pv + (size_t)o * (NH * CCH);
    const float* wxr = wx + (size_t)n * (NH * CCH);
    float acc = 0.f;
    for (int i = t; i < NH * CCH; i += 256)
        acc += pvr[i] * wxr[i];
    #pragma unroll
    for (int off = 32; off >= 1; off >>= 1)
        acc += __shfl_xor(acc, off, 64);
    if (ln == 0) pr[wv] = acc;
    __syncthreads();
    float base = gamma[0] * ((pr[0] + pr[1] + pr[2] + pr[3]) + proj_b[o]);

    const float4* x4 = (const float4*)(x + ((size_t)n * CCH + o) * HW);
    float4* o4 = (float4*)(out + ((size_t)n * CCH + o) * HW);
    #pragma unroll
    for (int j = 0; j < 4; ++j) {
        int idx = t + 256 * j;           // 1024 float4 per row
        float4 v = x4[idx];
        v.x += base; v.y += base; v.z += base; v.w += base;
        o4[idx] = v;
    }
}

extern "C" void kernel_launch(void* const* d_in, const int* in_sizes, int n_in,
                              void* d_out, int out_size, void* d_ws, size_t ws_size,
                              hipStream_t stream) {
    const float* x         = (const float*)d_in[0];
    const float* key_w     = (const float*)d_in[1];
    // d_in[2] offset_w, d_in[3] dconv_w, d_in[8] appr_bias_q: dead path (a cancels in softmax)
    const float* value_w   = (const float*)d_in[4];
    const float* proj_w    = (const float*)d_in[5];
    const float* proj_b    = (const float*)d_in[6];
    const float* appr_bias = (const float*)d_in[7];
    const float* gamma     = (const float*)d_in[9];
    float* out = (float*)d_out;

    float* ws    = (float*)d_ws;
    float* pv    = ws + WS_PV;
    float* bpart = ws + WS_BPART;
    float* wx    = ws + WS_WX;

    k_head   <<<1328, 256, 0, stream>>>(x, key_w, appr_bias, value_w, proj_w, ws);
    k_swx    <<<dim3(144, 2), 256, 0, stream>>>(x, bpart, wx);
    k_pofinal<<<1152, 256, 0, stream>>>(pv, proj_b, wx, x, gamma, out);
}

// Round 8
// 53.040 us; speedup vs baseline: 1.1719x; 1.1719x over previous
//
#include <hip/hip_runtime.h>

// NovelKQRAttention — algebraically collapsed, 4-kernel chain.
// energy = a[...,q,None] + b[...,None,k]; softmax over k => a cancels,
// attn = softmax_k(b) independent of q => deform-conv path is dead,
// attention output constant over spatial dims.
//
//   K1 k_bpart  : partial b[n,h,k] per 72-ch chunk (kb-slice inline), 64 blocks
//   K2 k_swx    : 8-chunk-sum (21 MB L2 redundancy) + softmax in LDS
//                 + wx for 16 channels/block (4/wave), 72 blocks
//   K3 k_ov     : ov[n,o] = value_w[o,:] . wx[n,h(o),:]  (1 wave/out, 288 blocks)
//   K4 k_pofinal: po = proj_w[o,:].ov[n,:] + proj_b; out row = gamma*po + x row
//                 (block per (n,o) row, 1152 blocks — streams 38 MB)

#define CCH 576
#define NH 9
#define HW 4096   // 64*64
#define KHW 1024  // 32*32
#define W 64
#define CHN 8     // channel chunks
#define CPC 72    // channels per chunk

// ws float offsets
#define WS_BPART 0                    // 8*2*9*1024 = 147456
#define WS_WX    147456               // 2*9*576    = 10368
#define WS_OV    (147456 + 10368)     // 2*576      = 1152

// grid (4 kblk, 2 n, 8 chunk), block 256. bpart layout [ch][n][h][k].
__global__ void k_bpart(const float* __restrict__ x, const float* __restrict__ key_w,
                        const float* __restrict__ appr_bias, float* __restrict__ bpart) {
    int k  = blockIdx.x * 256 + threadIdx.x;   // 0..1023
    int n  = blockIdx.y;
    int ch = blockIdx.z;
    int c0 = ch * CPC;

    __shared__ float ab[CCH];
    __shared__ float kbs[NH][CPC];
    for (int i = threadIdx.x; i < CCH; i += 256) ab[i] = appr_bias[i];
    __syncthreads();
    for (int t = threadIdx.x; t < NH * CPC; t += 256) {
        int h = t / CPC, cl = t % CPC;
        float s = 0.f;
        #pragma unroll 8
        for (int e = 0; e < 64; ++e)
            s += ab[h * 64 + e] * key_w[(size_t)(h * 64 + e) * CCH + c0 + cl];
        kbs[h][cl] = s;
    }
    __syncthreads();

    int ky = k >> 5, kx = k & 31;
    const float* xb = x + (size_t)n * CCH * HW + (size_t)c0 * HW + (size_t)(ky * 2) * W + kx * 2;
    float acc[NH];
    #pragma unroll
    for (int h = 0; h < NH; ++h) acc[h] = 0.f;
    #pragma unroll 8
    for (int cl = 0; cl < CPC; ++cl) {
        float xv = xb[(size_t)cl * HW];
        #pragma unroll
        for (int h = 0; h < NH; ++h) acc[h] += kbs[h][cl] * xv;
    }
    #pragma unroll
    for (int h = 0; h < NH; ++h)
        bpart[(((size_t)ch * 2 + n) * NH + h) * KHW + k] = acc[h];
}

// grid (36, 2 n), block 256 (4 waves).
// A: sum 8 bpart chunks into LDS sm[9][1024]  (72 blocks x 294 KB = 21 MB L2/L3)
// B: per-wave softmax of disjoint head rows.
// C: wave wv handles channels c = bid.x*16 + wv*4 + {0..3}.
__global__ void k_swx(const float* __restrict__ x, const float* __restrict__ bpart,
                      float* __restrict__ wx) {
    int n = blockIdx.y;
    int tid = threadIdx.x;
    int wv = tid >> 6, ln = tid & 63;
    __shared__ float sm[NH * KHW];   // 36 KB

    const float* bp = bpart + (size_t)n * NH * KHW;
    for (int i = tid; i < NH * KHW; i += 256) {
        float v = 0.f;
        #pragma unroll
        for (int ch = 0; ch < CHN; ++ch)
            v += bp[(size_t)ch * 2 * NH * KHW + i];
        sm[i] = v;
    }
    __syncthreads();

    for (int h = wv; h < NH; h += 4) {
        float* row = sm + h * KHW;
        float m = -1e30f;
        #pragma unroll
        for (int j = 0; j < 16; ++j) m = fmaxf(m, row[ln + 64 * j]);
        #pragma unroll
        for (int off = 32; off >= 1; off >>= 1) m = fmaxf(m, __shfl_xor(m, off, 64));
        float s = 0.f;
        #pragma unroll
        for (int j = 0; j < 16; ++j) {
            float e = __expf(row[ln + 64 * j] - m);
            row[ln + 64 * j] = e;
            s += e;
        }
        #pragma unroll
        for (int off = 32; off >= 1; off >>= 1) s += __shfl_xor(s, off, 64);
        float inv = 1.f / s;
        #pragma unroll
        for (int j = 0; j < 16; ++j) row[ln + 64 * j] *= inv;
    }
    __syncthreads();

    #pragma unroll
    for (int j2 = 0; j2 < 4; ++j2) {
        int c = blockIdx.x * 16 + wv * 4 + j2;
        const float* xb = x + ((size_t)n * CCH + c) * HW;
        float acc[NH];
        #pragma unroll
        for (int h = 0; h < NH; ++h) acc[h] = 0.f;
        #pragma unroll 4
        for (int j = 0; j < 16; ++j) {
            int k = ln + 64 * j;
            int ky = k >> 5, kx = k & 31;
            float xv = xb[(size_t)(ky * 2) * W + kx * 2];
            #pragma unroll
            for (int h = 0; h < NH; ++h) acc[h] += sm[h * KHW + k] * xv;
        }
        #pragma unroll
        for (int h = 0; h < NH; ++h) {
            float v = acc[h];
            #pragma unroll
            for (int off = 32; off >= 1; off >>= 1) v += __shfl_xor(v, off, 64);
            if (ln == 0) wx[((size_t)n * NH + h) * CCH + c] = v;
        }
    }
}

// one wave per output element; grid 288, block 256 (4 waves)
__global__ void k_ov(const float* __restrict__ value_w, const float* __restrict__ wx,
                     float* __restrict__ ov) {
    int g = blockIdx.x * 4 + (threadIdx.x >> 6);   // 0..1151
    int lane = threadIdx.x & 63;
    int n = g / CCH, o = g % CCH;
    int h = o >> 6;
    const float* vw  = value_w + (size_t)o * CCH;
    const float* wxr = wx + ((size_t)n * NH + h) * CCH;
    float acc = 0.f;
    #pragma unroll
    for (int j = 0; j < 9; ++j)
        acc += vw[lane + 64 * j] * wxr[lane + 64 * j];
    #pragma unroll
    for (int off = 32; off >= 1; off >>= 1)
        acc += __shfl_xor(acc, off, 64);
    if (lane == 0) ov[n * CCH + o] = acc;
}

// grid 1152 (= 2*576, one block per (n,o) row), block 256.
// Block-wide dot(proj_w[o,:], ov[n,:]) then stream out row = x row + base.
__global__ void k_pofinal(const float* __restrict__ proj_w, const float* __restrict__ proj_b,
                          const float* __restrict__ ov, const float* __restrict__ x,
                          const float* __restrict__ gamma, float* __restrict__ out) {
    int b = blockIdx.x;
    int n = b / CCH, o = b % CCH;
    int t = threadIdx.x;
    int wv = t >> 6, ln = t & 63;
    __shared__ float pr[4];

    const float* pw  = proj_w + (size_t)o * CCH;
    const float* ovr = ov + n * CCH;
    float acc = pw[t] * ovr[t] + pw[t + 256] * ovr[t + 256];
    if (t < 64) acc += pw[t + 512] * ovr[t + 512];
    #pragma unroll
    for (int off = 32; off >= 1; off >>= 1)
        acc += __shfl_xor(acc, off, 64);
    if (ln == 0) pr[wv] = acc;
    __syncthreads();
    float base = gamma[0] * ((pr[0] + pr[1] + pr[2] + pr[3]) + proj_b[o]);

    const float4* x4 = (const float4*)(x + ((size_t)n * CCH + o) * HW);
    float4* o4 = (float4*)(out + ((size_t)n * CCH + o) * HW);
    #pragma unroll
    for (int j = 0; j < 4; ++j) {
        int idx = t + 256 * j;           // 1024 float4 per row
        float4 v = x4[idx];
        v.x += base; v.y += base; v.z += base; v.w += base;
        o4[idx] = v;
    }
}

extern "C" void kernel_launch(void* const* d_in, const int* in_sizes, int n_in,
                              void* d_out, int out_size, void* d_ws, size_t ws_size,
                              hipStream_t stream) {
    const float* x         = (const float*)d_in[0];
    const float* key_w     = (const float*)d_in[1];
    // d_in[2] offset_w, d_in[3] dconv_w, d_in[8] appr_bias_q: dead path (a cancels in softmax)
    const float* value_w   = (const float*)d_in[4];
    const float* proj_w    = (const float*)d_in[5];
    const float* proj_b    = (const float*)d_in[6];
    const float* appr_bias = (const float*)d_in[7];
    const float* gamma     = (const float*)d_in[9];
    float* out = (float*)d_out;

    float* ws    = (float*)d_ws;
    float* bpart = ws + WS_BPART;
    float* wx    = ws + WS_WX;
    float* ov    = ws + WS_OV;

    k_bpart  <<<dim3(4, 2, CHN), 256, 0, stream>>>(x, key_w, appr_bias, bpart);
    k_swx    <<<dim3(36, 2), 256, 0, stream>>>(x, bpart, wx);
    k_ov     <<<288, 256, 0, stream>>>(value_w, wx, ov);
    k_pofinal<<<1152, 256, 0, stream>>>(proj_w, proj_b, ov, x, gamma, out);
}

// Round 9
// 41.823 us; speedup vs baseline: 1.4862x; 1.2682x over previous
//
#include <hip/hip_runtime.h>

// NovelKQRAttention — algebraically collapsed, 5-kernel chain.
// energy = a[...,q,None] + b[...,None,k]; softmax over k => a cancels,
// attn = softmax_k(b) independent of q => deform-conv path is dead,
// attention output constant over spatial dims.
//
//   K1 k_bpart  : partial b[n,h,k] per 36-ch chunk (kb-slice inline), 128 blocks;
//                 ALSO writes compact xkv[n,c,k] (removes later stride-2 gathers)
//   K2 k_softmax: sum 16 chunks + softmax over k=1024 -> p   (18 blocks, ~2us)
//   K3 k_wx     : wx[n,h,c] = sum_k p[h,k]*xkv[n,c,k], float4 reads, 288 blocks
//   K4 k_ov     : ov[n,o] = value_w[o,:] . wx[n,h(o),:]  (1 wave/out, 288 blocks)
//   K5 k_pofinal: po = proj_w[o,:].ov[n,:] + proj_b; out row = gamma*po + x row
//                 (block per (n,o) row, 1152 blocks — streams 38 MB)

#define CCH 576
#define NH 9
#define HW 4096   // 64*64
#define KHW 1024  // 32*32
#define W 64
#define CHN 16    // channel chunks
#define CPC 36    // channels per chunk

// ws float offsets
#define WS_XKV   0                           // 2*576*1024 = 1179648
#define WS_BPART 1179648                     // 16*2*9*1024 = 294912 (layout [n][ch][h][k])
#define WS_P     (1179648 + 294912)          // 2*9*1024 = 18432
#define WS_WX    (1179648 + 294912 + 18432)  // 2*9*576  = 10368
#define WS_OV    (1179648 + 294912 + 18432 + 10368)  // 2*576 = 1152

// grid (4 kblk, 2 n, 16 chunk), block 256.
__global__ void k_bpart(const float* __restrict__ x, const float* __restrict__ key_w,
                        const float* __restrict__ appr_bias, float* __restrict__ bpart,
                        float* __restrict__ xkv) {
    int k  = blockIdx.x * 256 + threadIdx.x;   // 0..1023
    int n  = blockIdx.y;
    int ch = blockIdx.z;
    int c0 = ch * CPC;

    __shared__ float ab[CCH];
    __shared__ float kbs[NH][CPC];
    for (int i = threadIdx.x; i < CCH; i += 256) ab[i] = appr_bias[i];
    __syncthreads();
    for (int t = threadIdx.x; t < NH * CPC; t += 256) {
        int h = t / CPC, cl = t % CPC;
        float s = 0.f;
        #pragma unroll 8
        for (int e = 0; e < 64; ++e)
            s += ab[h * 64 + e] * key_w[(size_t)(h * 64 + e) * CCH + c0 + cl];
        kbs[h][cl] = s;
    }
    __syncthreads();

    int ky = k >> 5, kx = k & 31;
    const float* xb = x + (size_t)n * CCH * HW + (size_t)c0 * HW + (size_t)(ky * 2) * W + kx * 2;
    float acc[NH];
    #pragma unroll
    for (int h = 0; h < NH; ++h) acc[h] = 0.f;
    for (int cl = 0; cl < CPC; ++cl) {
        float xv = xb[(size_t)cl * HW];
        xkv[((size_t)n * CCH + c0 + cl) * KHW + k] = xv;   // compact x_kv
        #pragma unroll
        for (int h = 0; h < NH; ++h) acc[h] += kbs[h][cl] * xv;
    }
    #pragma unroll
    for (int h = 0; h < NH; ++h)
        bpart[(((size_t)n * CHN + ch) * NH + h) * KHW + k] = acc[h];
}

// grid 18 (= n*9), block 256. Sum 16 chunks, softmax over k=1024, write p.
__global__ void k_softmax(const float* __restrict__ bpart, float* __restrict__ p) {
    int nh = blockIdx.x;
    int n = nh / NH, h = nh % NH;
    int tid = threadIdx.x;
    int wave = tid >> 6, lane = tid & 63;
    float s[4];
    #pragma unroll
    for (int j = 0; j < 4; ++j) {
        int k = tid + j * 256;
        float v = 0.f;
        #pragma unroll
        for (int ch = 0; ch < CHN; ++ch)
            v += bpart[(((size_t)n * CHN + ch) * NH + h) * KHW + k];
        s[j] = v;
    }
    float m = fmaxf(fmaxf(s[0], s[1]), fmaxf(s[2], s[3]));
    #pragma unroll
    for (int off = 32; off >= 1; off >>= 1)
        m = fmaxf(m, __shfl_xor(m, off, 64));
    __shared__ float redm[4];
    if (lane == 0) redm[wave] = m;
    __syncthreads();
    m = fmaxf(fmaxf(redm[0], redm[1]), fmaxf(redm[2], redm[3]));
    float e[4], lsum = 0.f;
    #pragma unroll
    for (int j = 0; j < 4; ++j) { e[j] = __expf(s[j] - m); lsum += e[j]; }
    #pragma unroll
    for (int off = 32; off >= 1; off >>= 1)
        lsum += __shfl_xor(lsum, off, 64);
    __shared__ float reds[4];
    if (lane == 0) reds[wave] = lsum;
    __syncthreads();
    float inv = 1.f / (reds[0] + reds[1] + reds[2] + reds[3]);
    #pragma unroll
    for (int j = 0; j < 4; ++j)
        p[(size_t)nh * KHW + tid + j * 256] = e[j] * inv;
}

// grid (144 c-tiles, 2 n), block 256 (4 waves). Wave = 1 channel; float4 reads.
__global__ void k_wx(const float* __restrict__ xkv, const float* __restrict__ p,
                     float* __restrict__ wx) {
    int n = blockIdx.y;
    int tid = threadIdx.x;
    int wv = tid >> 6, ln = tid & 63;
    __shared__ float ps[NH * KHW];   // 36 KB
    const float4* p4 = (const float4*)(p + (size_t)n * NH * KHW);
    float4* ps4 = (float4*)ps;
    for (int i = tid; i < NH * KHW / 4; i += 256) ps4[i] = p4[i];
    __syncthreads();

    int c = blockIdx.x * 4 + wv;   // 0..575
    const float4* xr = (const float4*)(xkv + ((size_t)n * CCH + c) * KHW);
    float acc[NH];
    #pragma unroll
    for (int h = 0; h < NH; ++h) acc[h] = 0.f;
    #pragma unroll
    for (int j = 0; j < 4; ++j) {
        float4 xv = xr[ln + 64 * j];
        #pragma unroll
        for (int h = 0; h < NH; ++h) {
            float4 pv = ((const float4*)(ps + h * KHW))[ln + 64 * j];
            acc[h] += pv.x * xv.x + pv.y * xv.y + pv.z * xv.z + pv.w * xv.w;
        }
    }
    #pragma unroll
    for (int h = 0; h < NH; ++h) {
        float v = acc[h];
        #pragma unroll
        for (int off = 32; off >= 1; off >>= 1) v += __shfl_xor(v, off, 64);
        if (ln == 0) wx[((size_t)n * NH + h) * CCH + c] = v;
    }
}

// one wave per output element; grid 288, block 256 (4 waves)
__global__ void k_ov(const float* __restrict__ value_w, const float* __restrict__ wx,
                     float* __restrict__ ov) {
    int g = blockIdx.x * 4 + (threadIdx.x >> 6);   // 0..1151
    int lane = threadIdx.x & 63;
    int n = g / CCH, o = g % CCH;
    int h = o >> 6;
    const float* vw  = value_w + (size_t)o * CCH;
    const float* wxr = wx + ((size_t)n * NH + h) * CCH;
    float acc = 0.f;
    #pragma unroll
    for (int j = 0; j < 9; ++j)
        acc += vw[lane + 64 * j] * wxr[lane + 64 * j];
    #pragma unroll
    for (int off = 32; off >= 1; off >>= 1)
        acc += __shfl_xor(acc, off, 64);
    if (lane == 0) ov[n * CCH + o] = acc;
}

// grid 1152 (= 2*576, one block per (n,o) row), block 256.
// Block-wide dot(proj_w[o,:], ov[n,:]) then stream out row = x row + base.
__global__ void k_pofinal(const float* __restrict__ proj_w, const float* __restrict__ proj_b,
                          const float* __restrict__ ov, const float* __restrict__ x,
                          const float* __restrict__ gamma, float* __restrict__ out) {
    int b = blockIdx.x;
    int n = b / CCH, o = b % CCH;
    int t = threadIdx.x;
    int wv = t >> 6, ln = t & 63;
    __shared__ float pr[4];

    const float* pw  = proj_w + (size_t)o * CCH;
    const float* ovr = ov + n * CCH;
    float acc = pw[t] * ovr[t] + pw[t + 256] * ovr[t + 256];
    if (t < 64) acc += pw[t + 512] * ovr[t + 512];
    #pragma unroll
    for (int off = 32; off >= 1; off >>= 1)
        acc += __shfl_xor(acc, off, 64);
    if (ln == 0) pr[wv] = acc;
    __syncthreads();
    float base = gamma[0] * ((pr[0] + pr[1] + pr[2] + pr[3]) + proj_b[o]);

    const float4* x4 = (const float4*)(x + ((size_t)n * CCH + o) * HW);
    float4* o4 = (float4*)(out + ((size_t)n * CCH + o) * HW);
    #pragma unroll
    for (int j = 0; j < 4; ++j) {
        int idx = t + 256 * j;           // 1024 float4 per row
        float4 v = x4[idx];
        v.x += base; v.y += base; v.z += base; v.w += base;
        o4[idx] = v;
    }
}

extern "C" void kernel_launch(void* const* d_in, const int* in_sizes, int n_in,
                              void* d_out, int out_size, void* d_ws, size_t ws_size,
                              hipStream_t stream) {
    const float* x         = (const float*)d_in[0];
    const float* key_w     = (const float*)d_in[1];
    // d_in[2] offset_w, d_in[3] dconv_w, d_in[8] appr_bias_q: dead path (a cancels in softmax)
    const float* value_w   = (const float*)d_in[4];
    const float* proj_w    = (const float*)d_in[5];
    const float* proj_b    = (const float*)d_in[6];
    const float* appr_bias = (const float*)d_in[7];
    const float* gamma     = (const float*)d_in[9];
    float* out = (float*)d_out;

    float* ws    = (float*)d_ws;
    float* xkv   = ws + WS_XKV;
    float* bpart = ws + WS_BPART;
    float* p     = ws + WS_P;
    float* wx    = ws + WS_WX;
    float* ov    = ws + WS_OV;

    k_bpart  <<<dim3(4, 2, CHN), 256, 0, stream>>>(x, key_w, appr_bias, bpart, xkv);
    k_softmax<<<18, 256, 0, stream>>>(bpart, p);
    k_wx     <<<dim3(144, 2), 256, 0, stream>>>(xkv, p, wx);
    k_ov     <<<288, 256, 0, stream>>>(value_w, wx, ov);
    k_pofinal<<<1152, 256, 0, stream>>>(proj_w, proj_b, ov, x, gamma, out);
}